// Round 3
// baseline (710.264 us; speedup 1.0000x reference)
//
#include <hip/hip_runtime.h>
#include <math.h>

#define DEV __device__ __forceinline__

// ---- ws float layout (total 4416 floats ~ 17.7 KB) ----
// [0..3] : reduction slots (bit patterns of non-negative floats)
static constexpr int W1S = 16;   // 64 scales
static constexpr int W2S = 80;   // 32
static constexpr int W3S = 112;  // 32
static constexpr int W4S = 144;  // 5 (padded)
static constexpr int W1Q = 160;  // 64x16 fp32-valued ints
static constexpr int W2Q = 1184; // 32x64
static constexpr int W3Q = 3232; // 32x32
static constexpr int W4Q = 4256; // 5x32

DEV float qact(float v, float inv) {
    // round-half-even, clip to int16 range
    return fminf(fmaxf(rintf(v * inv), -32768.f), 32767.f);
}

DEV float qbias(float b, float bs) {
    float q = rintf(b / bs);
    return fminf(fmaxf(q, -2.147483648e9f), 2.147483648e9f);
}

DEV void reduceAndAtomicMax(float v, unsigned int* slot) {
    #pragma unroll
    for (int off = 32; off; off >>= 1) v = fmaxf(v, __shfl_xor(v, off));
    __shared__ float sm[4];
    const int wid = threadIdx.x >> 6;
    if ((threadIdx.x & 63) == 0) sm[wid] = v;
    __syncthreads();
    if (threadIdx.x == 0) {
        float m = fmaxf(fmaxf(sm[0], sm[1]), fmaxf(sm[2], sm[3]));
        atomicMax(slot, __float_as_uint(m)); // non-negative: bit order == value order
    }
}

// ---- setup: quantize weights (stored as float-valued ints) ----
__global__ __launch_bounds__(256) void k_quantw(const float* __restrict__ W1,
                                                const float* __restrict__ W2,
                                                const float* __restrict__ W3,
                                                const float* __restrict__ W4,
                                                float* __restrict__ ws) {
    const int t = threadIdx.x;
    if (t >= 192 && t < 196) ((unsigned int*)ws)[t - 192] = 0u;

    const float* W = nullptr; int row = -1, cols = 0; float* dq = nullptr; float* dsc = nullptr;
    if (t < 64)       { W = W1; row = t;       cols = 16; dq = ws + W1Q + row * 16; dsc = ws + W1S + row; }
    else if (t < 96)  { W = W2; row = t - 64;  cols = 64; dq = ws + W2Q + row * 64; dsc = ws + W2S + row; }
    else if (t < 128) { W = W3; row = t - 96;  cols = 32; dq = ws + W3Q + row * 32; dsc = ws + W3S + row; }
    else if (t < 133) { W = W4; row = t - 128; cols = 32; dq = ws + W4Q + row * 32; dsc = ws + W4S + row; }
    if (row >= 0) {
        const float* src = W + row * cols;
        float m = 0.f;
        for (int i = 0; i < cols; i++) m = fmaxf(m, fabsf(src[i]));
        float s = fmaxf(m * (1.0f / 127.0f), 1e-8f);
        *dsc = s;
        for (int i = 0; i < cols; i++) {
            float q = rintf(src[i] / s);
            dq[i] = fminf(fmaxf(q, -128.f), 127.f);
        }
    }
}

// ---- K0: max|x| ----
__global__ __launch_bounds__(256) void k_absmax(const float4* __restrict__ x,
                                                unsigned int* __restrict__ slots, int n4) {
    float m = 0.f;
    for (int i = blockIdx.x * blockDim.x + threadIdx.x; i < n4; i += gridDim.x * blockDim.x) {
        float4 v = x[i];
        m = fmaxf(m, fmaxf(fmaxf(fabsf(v.x), fabsf(v.y)), fmaxf(fabsf(v.z), fabsf(v.w))));
    }
    reduceAndAtomicMax(m, slots + 0);
}

// ---- linear layer, 2 rows per thread, float4 weight loads, 4 fma chains ----
template <int IN, int OUT, bool RELU>
DEV void layer2(const float* __restrict__ wq, const float2* __restrict__ bias,
                const float* __restrict__ in0, const float* __restrict__ in1,
                float* __restrict__ out0, float* __restrict__ out1) {
    #pragma unroll
    for (int o = 0; o < OUT; o++) {
        const float4* __restrict__ wr = (const float4*)(wq + o * IN);
        float a0 = 0.f, b0 = 0.f, a1 = 0.f, b1 = 0.f;
        #pragma unroll
        for (int k = 0; k < IN / 8; k++) {
            float4 w0 = wr[2 * k + 0];
            float4 w1 = wr[2 * k + 1];
            const int i0 = 8 * k, i1 = 8 * k + 4;
            a0 = fmaf(in0[i0 + 0], w0.x, a0);  a1 = fmaf(in1[i0 + 0], w0.x, a1);
            b0 = fmaf(in0[i1 + 0], w1.x, b0);  b1 = fmaf(in1[i1 + 0], w1.x, b1);
            a0 = fmaf(in0[i0 + 1], w0.y, a0);  a1 = fmaf(in1[i0 + 1], w0.y, a1);
            b0 = fmaf(in0[i1 + 1], w1.y, b0);  b1 = fmaf(in1[i1 + 1], w1.y, b1);
            a0 = fmaf(in0[i0 + 2], w0.z, a0);  a1 = fmaf(in1[i0 + 2], w0.z, a1);
            b0 = fmaf(in0[i1 + 2], w1.z, b0);  b1 = fmaf(in1[i1 + 2], w1.z, b1);
            a0 = fmaf(in0[i0 + 3], w0.w, a0);  a1 = fmaf(in1[i0 + 3], w0.w, a1);
            b0 = fmaf(in0[i1 + 3], w1.w, b0);  b1 = fmaf(in1[i1 + 3], w1.w, b1);
        }
        float2 bb = bias[o];
        float v0 = ((a0 + b0) + bb.x) * bb.y;
        float v1 = ((a1 + b1) + bb.x) * bb.y;
        out0[o] = RELU ? fmaxf(v0, 0.f) : v0;
        out1[o] = RELU ? fmaxf(v1, 0.f) : v1;
    }
}

template <int N>
DEV void quant_arr(float* h, float inv) { // h >= 0 (post-relu)
    #pragma unroll
    for (int i = 0; i < N; i++) h[i] = fminf(rintf(h[i] * inv), 32767.f);
}

template <int N>
DEV float maxarr(const float* h) {
    float m = 0.f;
    #pragma unroll
    for (int i = 0; i < N; i++) m = fmaxf(m, h[i]);
    return m;
}

DEV void softmax_store(const float* lg, float* dst) {
    float m = lg[0];
    #pragma unroll
    for (int i = 1; i < 5; i++) m = fmaxf(m, lg[i]);
    float e[5], s = 0.f;
    #pragma unroll
    for (int i = 0; i < 5; i++) { e[i] = expf(lg[i] - m); s += e[i]; }
    const float r = 1.f / s;
    #pragma unroll
    for (int i = 0; i < 5; i++) dst[i] = e[i] * r;
}

// ---- staged forward (2 rows/thread): stages 1..3 reduce max, stage 4 writes out ----
template <int STAGE>
DEV void stage_body(const float* __restrict__ x,
                    const float* __restrict__ b1, const float* __restrict__ b2,
                    const float* __restrict__ b3, const float* __restrict__ b4,
                    const float* __restrict__ ws, unsigned int* __restrict__ slots,
                    float* __restrict__ out) {
    __shared__ float2 B1[64], B2[32], B3[32], B4[8];
    const int t = threadIdx.x;

    const float s0 = fmaxf(__uint_as_float(slots[0]) * (1.f / 32767.f), 1e-8f);
    float s1 = 1.f, s2 = 1.f, s3 = 1.f;
    if (STAGE >= 2) s1 = fmaxf(__uint_as_float(slots[1]) * (1.f / 32767.f), 1e-8f);
    if (STAGE >= 3) s2 = fmaxf(__uint_as_float(slots[2]) * (1.f / 32767.f), 1e-8f);
    if (STAGE >= 4) s3 = fmaxf(__uint_as_float(slots[3]) * (1.f / 32767.f), 1e-8f);

    if (t < 64) { float bs = ws[W1S + t] * s0; B1[t] = make_float2(qbias(b1[t], bs), bs); }
    if (STAGE >= 2 && t < 32) { float bs = ws[W2S + t] * s1; B2[t] = make_float2(qbias(b2[t], bs), bs); }
    if (STAGE >= 3 && t < 32) { float bs = ws[W3S + t] * s2; B3[t] = make_float2(qbias(b3[t], bs), bs); }
    if (STAGE >= 4 && t < 5)  { float bs = ws[W4S + t] * s3; B4[t] = make_float2(qbias(b4[t], bs), bs); }
    __syncthreads();

    const size_t r0 = (size_t)blockIdx.x * 512 + t; // second row: r0 + 256

    float xq0[16], xq1[16];
    {
        const float4* xr0 = (const float4*)(x + r0 * 16);
        const float4* xr1 = (const float4*)(x + (r0 + 256) * 16);
        const float inv0 = 1.f / s0;
        #pragma unroll
        for (int c = 0; c < 4; c++) {
            float4 v0 = xr0[c], v1 = xr1[c];
            xq0[4 * c + 0] = qact(v0.x, inv0);  xq1[4 * c + 0] = qact(v1.x, inv0);
            xq0[4 * c + 1] = qact(v0.y, inv0);  xq1[4 * c + 1] = qact(v1.y, inv0);
            xq0[4 * c + 2] = qact(v0.z, inv0);  xq1[4 * c + 2] = qact(v1.z, inv0);
            xq0[4 * c + 3] = qact(v0.w, inv0);  xq1[4 * c + 3] = qact(v1.w, inv0);
        }
    }

    float h1a[64], h1b[64];
    layer2<16, 64, true>(ws + W1Q, B1, xq0, xq1, h1a, h1b);
    if (STAGE == 1) {
        reduceAndAtomicMax(fmaxf(maxarr<64>(h1a), maxarr<64>(h1b)), slots + 1);
        return;
    }
    { const float inv = 1.f / s1; quant_arr<64>(h1a, inv); quant_arr<64>(h1b, inv); }

    float h2a[32], h2b[32];
    layer2<64, 32, true>(ws + W2Q, B2, h1a, h1b, h2a, h2b);
    if (STAGE == 2) {
        reduceAndAtomicMax(fmaxf(maxarr<32>(h2a), maxarr<32>(h2b)), slots + 2);
        return;
    }
    { const float inv = 1.f / s2; quant_arr<32>(h2a, inv); quant_arr<32>(h2b, inv); }

    float h3a[32], h3b[32];
    layer2<32, 32, true>(ws + W3Q, B3, h2a, h2b, h3a, h3b);
    if (STAGE == 3) {
        reduceAndAtomicMax(fmaxf(maxarr<32>(h3a), maxarr<32>(h3b)), slots + 3);
        return;
    }
    { const float inv = 1.f / s3; quant_arr<32>(h3a, inv); quant_arr<32>(h3b, inv); }

    float lga[5], lgb[5];
    layer2<32, 5, false>(ws + W4Q, B4, h3a, h3b, lga, lgb);

    softmax_store(lga, out + r0 * 5);
    softmax_store(lgb, out + (r0 + 256) * 5);
}

__global__ __launch_bounds__(256) void k_s1(const float* x, const float* b1, const float* b2,
                                            const float* b3, const float* b4, const float* ws,
                                            unsigned int* slots, float* out) {
    stage_body<1>(x, b1, b2, b3, b4, ws, slots, out);
}
__global__ __launch_bounds__(256) void k_s2(const float* x, const float* b1, const float* b2,
                                            const float* b3, const float* b4, const float* ws,
                                            unsigned int* slots, float* out) {
    stage_body<2>(x, b1, b2, b3, b4, ws, slots, out);
}
__global__ __launch_bounds__(256) void k_s3(const float* x, const float* b1, const float* b2,
                                            const float* b3, const float* b4, const float* ws,
                                            unsigned int* slots, float* out) {
    stage_body<3>(x, b1, b2, b3, b4, ws, slots, out);
}
__global__ __launch_bounds__(256) void k_s4(const float* x, const float* b1, const float* b2,
                                            const float* b3, const float* b4, const float* ws,
                                            unsigned int* slots, float* out) {
    stage_body<4>(x, b1, b2, b3, b4, ws, slots, out);
}

extern "C" void kernel_launch(void* const* d_in, const int* in_sizes, int n_in,
                              void* d_out, int out_size, void* d_ws, size_t ws_size,
                              hipStream_t stream) {
    const float* x  = (const float*)d_in[0];
    const float* W1 = (const float*)d_in[1];
    const float* b1 = (const float*)d_in[2];
    const float* W2 = (const float*)d_in[3];
    const float* b2 = (const float*)d_in[4];
    const float* W3 = (const float*)d_in[5];
    const float* b3 = (const float*)d_in[6];
    const float* W4 = (const float*)d_in[7];
    const float* b4 = (const float*)d_in[8];
    float* out = (float*)d_out;
    float* ws = (float*)d_ws;
    unsigned int* slots = (unsigned int*)d_ws;

    const int B = in_sizes[0] / 16;      // 1 << 20
    const int blocks = (B + 511) / 512;  // 2048 (2 rows per thread)

    k_quantw<<<1, 256, 0, stream>>>(W1, W2, W3, W4, ws);
    k_absmax<<<4096, 256, 0, stream>>>((const float4*)x, slots, (in_sizes[0] + 3) / 4);
    k_s1<<<blocks, 256, 0, stream>>>(x, b1, b2, b3, b4, ws, slots, out);
    k_s2<<<blocks, 256, 0, stream>>>(x, b1, b2, b3, b4, ws, slots, out);
    k_s3<<<blocks, 256, 0, stream>>>(x, b1, b2, b3, b4, ws, slots, out);
    k_s4<<<blocks, 256, 0, stream>>>(x, b1, b2, b3, b4, ws, slots, out);
}

// Round 4
// 315.440 us; speedup vs baseline: 2.2517x; 2.2517x over previous
//
#include <hip/hip_runtime.h>
#include <math.h>

#define DEV __device__ __forceinline__

typedef short s16x8 __attribute__((ext_vector_type(8)));
typedef float f32x4 __attribute__((ext_vector_type(4)));

// ---- ws dword layout ----
// [0..3]: reduction slots (bit patterns of non-negative floats)
static constexpr int W1S = 16;   // 64 per-row weight scales
static constexpr int W2S = 80;   // 32
static constexpr int W3S = 112;  // 32
static constexpr int W4S = 144;  // 5
static constexpr int F0  = 256;  // 11 B-fragments, each 64 lanes x int4 (256 dwords)
// frag ids: 0..3 = L1 nt0..3 | 4..7 = L2 (kk*2+nt) | 8..9 = L3 nt | 10 = L4

static constexpr int TPW = 8;    // tiles (16 rows) per wave

DEV float qbias(float b, float bs) {
    float q = rintf(b / bs);
    return fminf(fmaxf(q, -2.147483648e9f), 2.147483648e9f);
}

DEV unsigned short bf16b(float f) {  // values used are exact in bf16 -> truncate
    return (unsigned short)(__float_as_uint(f) >> 16);
}

DEV void reduceAndAtomicMax(float v, unsigned int* slot) {
    #pragma unroll
    for (int off = 32; off; off >>= 1) v = fmaxf(v, __shfl_xor(v, off));
    __shared__ float sm[4];
    const int wid = threadIdx.x >> 6;
    if ((threadIdx.x & 63) == 0) sm[wid] = v;
    __syncthreads();
    if (threadIdx.x == 0) {
        float m = fmaxf(fmaxf(sm[0], sm[1]), fmaxf(sm[2], sm[3]));
        atomicMax(slot, __float_as_uint(m)); // non-negative: bit order == value order
    }
}

// ---- setup: quantize weights, emit MFMA B-fragments (bf16 bits), zero slots ----
__global__ __launch_bounds__(256) void k_quantw(const float* __restrict__ W1,
                                                const float* __restrict__ W2,
                                                const float* __restrict__ W3,
                                                const float* __restrict__ W4,
                                                float* __restrict__ wsf) {
    __shared__ int wq1[64 * 16], wq2[32 * 64], wq3[32 * 32], wq4[5 * 32];
    int* wsi = (int*)wsf;
    const int t = threadIdx.x;
    if (t < 4) ((unsigned int*)wsf)[t] = 0u;

    const float* W = nullptr; int row = -1, cols = 0; int* dq = nullptr; float* dsc = nullptr;
    if (t < 64)       { W = W1; row = t;       cols = 16; dq = wq1 + row * 16; dsc = wsf + W1S + row; }
    else if (t < 96)  { W = W2; row = t - 64;  cols = 64; dq = wq2 + row * 64; dsc = wsf + W2S + row; }
    else if (t < 128) { W = W3; row = t - 96;  cols = 32; dq = wq3 + row * 32; dsc = wsf + W3S + row; }
    else if (t < 133) { W = W4; row = t - 128; cols = 32; dq = wq4 + row * 32; dsc = wsf + W4S + row; }
    if (row >= 0) {
        const float* src = W + row * cols;
        float m = 0.f;
        for (int i = 0; i < cols; i++) m = fmaxf(m, fabsf(src[i]));
        float s = fmaxf(m * (1.0f / 127.0f), 1e-8f);
        *dsc = s;
        for (int i = 0; i < cols; i++) {
            float q = fminf(fmaxf(rintf(src[i] / s), -128.f), 127.f);
            dq[i] = (int)q;
        }
    }
    __syncthreads();

    // B-fragment layout for mfma_f32_16x16x32_bf16:
    // lane l holds B[k = (l>>4)*8 + e][col = l&15], e = 0..7 (8 bf16 = int4)
    for (int sIdx = t; sIdx < 11 * 64; sIdx += 256) {
        const int f = sIdx >> 6, l = sIdx & 63;
        const int grp = l >> 4, li = l & 15;
        int dw[4];
        #pragma unroll
        for (int d = 0; d < 4; d++) {
            unsigned int hv[2];
            #pragma unroll
            for (int h = 0; h < 2; h++) {
                const int e = 2 * d + h;
                const int k = grp * 8 + e;          // 0..31
                int wv;
                if (f < 4)        wv = wq1[(f * 16 + li) * 16 + (k & 15)];            // L1, hi|lo dup via &15
                else if (f < 8)   { int kk = (f - 4) >> 1, nt = (f - 4) & 1;
                                    wv = wq2[(nt * 16 + li) * 64 + kk * 32 + k]; }    // L2
                else if (f < 10)  wv = wq3[((f - 8) * 16 + li) * 32 + k];             // L3
                else              wv = (li < 5) ? wq4[li * 32 + k] : 0;               // L4 (pad cols)
                hv[h] = bf16b((float)wv);
            }
            dw[d] = (int)(hv[0] | (hv[1] << 16));
        }
        ((int4*)(wsi + F0))[f * 64 + l] = make_int4(dw[0], dw[1], dw[2], dw[3]);
    }
}

// ---- K0: max|x| ----
__global__ __launch_bounds__(256) void k_absmax(const float4* __restrict__ x,
                                                unsigned int* __restrict__ slots, int n4) {
    float m = 0.f;
    for (int i = blockIdx.x * blockDim.x + threadIdx.x; i < n4; i += gridDim.x * blockDim.x) {
        float4 v = x[i];
        m = fmaxf(m, fmaxf(fmaxf(fabsf(v.x), fabsf(v.y)), fmaxf(fabsf(v.z), fabsf(v.w))));
    }
    reduceAndAtomicMax(m, slots + 0);
}

// ---- staged MFMA forward ----
// Per wave: 16-row tile; hi/lo bf16 split makes int16 x int8 products exact.
template <int STAGE>
DEV void stage_body(const float* __restrict__ x,
                    const float* __restrict__ b1, const float* __restrict__ b2,
                    const float* __restrict__ b3, const float* __restrict__ b4,
                    const float* __restrict__ wsf, unsigned int* __restrict__ slots,
                    float* __restrict__ out) {
    __shared__ __align__(16) unsigned char smem[45184];
    const int t = threadIdx.x;
    const int w = t >> 6, l = t & 63;
    const int grp = l >> 4, li = l & 15;

    float2* B1s = (float2*)(smem + 44032);
    float2* B2s = (float2*)(smem + 44544);
    float2* B3s = (float2*)(smem + 44800);
    float2* B4s = (float2*)(smem + 45056);

    const float s0 = fmaxf(__uint_as_float(slots[0]) * (1.f / 32767.f), 1e-8f);
    float s1 = 1.f, s2 = 1.f, s3 = 1.f;
    if (STAGE >= 2) s1 = fmaxf(__uint_as_float(slots[1]) * (1.f / 32767.f), 1e-8f);
    if (STAGE >= 3) s2 = fmaxf(__uint_as_float(slots[2]) * (1.f / 32767.f), 1e-8f);
    if (STAGE >= 4) s3 = fmaxf(__uint_as_float(slots[3]) * (1.f / 32767.f), 1e-8f);

    if (t < 64) { float bs = wsf[W1S + t] * s0; B1s[t] = make_float2(qbias(b1[t], bs), bs); }
    if (STAGE >= 2 && t < 32) { float bs = wsf[W2S + t] * s1; B2s[t] = make_float2(qbias(b2[t], bs), bs); }
    if (STAGE >= 3 && t < 32) { float bs = wsf[W3S + t] * s2; B3s[t] = make_float2(qbias(b3[t], bs), bs); }
    if (STAGE >= 4 && t < 16) {
        float bs = (t < 5) ? wsf[W4S + t] * s3 : 1.f;
        float bi = (t < 5) ? qbias(b4[t], bs) : 0.f;
        B4s[t] = make_float2(bi, bs);
    }
    __syncthreads();

    // B-fragments (persist in VGPRs across all tiles)
    const int4* fr = (const int4*)((const int*)wsf + F0);
    s16x8 bf1[4], bf2[4], bf3[2], bf4;
    #pragma unroll
    for (int i = 0; i < 4; i++) bf1[i] = __builtin_bit_cast(s16x8, fr[i * 64 + l]);
    if (STAGE >= 2) {
        #pragma unroll
        for (int i = 0; i < 4; i++) bf2[i] = __builtin_bit_cast(s16x8, fr[(4 + i) * 64 + l]);
    }
    if (STAGE >= 3) {
        #pragma unroll
        for (int i = 0; i < 2; i++) bf3[i] = __builtin_bit_cast(s16x8, fr[(8 + i) * 64 + l]);
    }
    if (STAGE >= 4) bf4 = __builtin_bit_cast(s16x8, fr[10 * 64 + l]);

    float2 bb1[4], bb2[2], bb3[2], bb4;
    #pragma unroll
    for (int nt = 0; nt < 4; nt++) bb1[nt] = B1s[li + nt * 16];
    if (STAGE >= 2) { bb2[0] = B2s[li]; bb2[1] = B2s[li + 16]; }
    if (STAGE >= 3) { bb3[0] = B3s[li]; bb3[1] = B3s[li + 16]; }
    if (STAGE >= 4) { bb4 = B4s[li]; }

    // per-wave LDS planes (bf16 bits), padded strides to spread banks
    unsigned short* ah1 = (unsigned short*)(smem + w * 11008); // [16][72]
    unsigned short* al1 = ah1 + 1152;
    unsigned short* ah2 = al1 + 1152;                          // [16][40]
    unsigned short* al2 = ah2 + 640;
    unsigned short* ah3 = al2 + 640;                           // [16][40]
    unsigned short* al3 = ah3 + 640;
    float* smx = (float*)(smem + w * 11008 + 9728);            // [16][20] f32

    const float inv0 = 1.f / s0, inv1 = 1.f / s1, inv2 = 1.f / s2, inv3 = 1.f / s3;
    float vmax = 0.f;

    const size_t tile0 = ((size_t)blockIdx.x * 4 + w) * (size_t)TPW;
    for (int it = 0; it < TPW; ++it) {
        const size_t row0 = (tile0 + it) * 16;

        // ---- L1 A-fragment straight from x: lane row = li, k = grp*8+e ----
        // k<16 -> hi plane (q - al, multiple of 256), k>=16 -> lo plane (al)
        s16x8 a1;
        {
            const float4* xr = (const float4*)(x + (row0 + li) * 16 + (grp & 1) * 8);
            float4 v0 = xr[0], v1 = xr[1];
            float xv[8] = {v0.x, v0.y, v0.z, v0.w, v1.x, v1.y, v1.z, v1.w};
            const bool hi = (grp < 2);
            #pragma unroll
            for (int e = 0; e < 8; e++) {
                int q = (int)fminf(fmaxf(rintf(xv[e] * inv0), -32768.f), 32767.f);
                int al = (q << 24) >> 24;
                float fv = hi ? (float)(q - al) : (float)al;
                a1[e] = (short)bf16b(fv);
            }
        }
        f32x4 acc1[4];
        #pragma unroll
        for (int nt = 0; nt < 4; nt++) {
            acc1[nt] = f32x4{bb1[nt].x, bb1[nt].x, bb1[nt].x, bb1[nt].x};
            acc1[nt] = __builtin_amdgcn_mfma_f32_16x16x32_bf16(a1, bf1[nt], acc1[nt], 0, 0, 0);
        }
        if (STAGE == 1) {
            #pragma unroll
            for (int nt = 0; nt < 4; nt++)
                #pragma unroll
                for (int r = 0; r < 4; r++)
                    vmax = fmaxf(vmax, acc1[nt][r] * bb1[nt].y);  // vmax>=0 => implicit relu
            continue;
        }

        // ---- h1 -> quant/split -> LDS planes ----
        #pragma unroll
        for (int nt = 0; nt < 4; nt++)
            #pragma unroll
            for (int r = 0; r < 4; r++) {
                float h = fmaxf(acc1[nt][r] * bb1[nt].y, 0.f);
                int q = (int)fminf(rintf(h * inv1), 32767.f);
                int al = (q << 24) >> 24;
                int idx = (grp * 4 + r) * 72 + li + nt * 16;
                ah1[idx] = bf16b((float)(q - al));
                al1[idx] = bf16b((float)al);
            }
        asm volatile("" ::: "memory");

        // ---- L2: K=128 stacked (4 chunks) ----
        f32x4 acc2[2];
        #pragma unroll
        for (int nt = 0; nt < 2; nt++)
            acc2[nt] = f32x4{bb2[nt].x, bb2[nt].x, bb2[nt].x, bb2[nt].x};
        #pragma unroll
        for (int kk = 0; kk < 4; kk++) {
            const unsigned short* src = (kk < 2) ? ah1 : al1;
            s16x8 a2 = *(const s16x8*)(src + li * 72 + (kk & 1) * 32 + grp * 8);
            #pragma unroll
            for (int nt = 0; nt < 2; nt++)
                acc2[nt] = __builtin_amdgcn_mfma_f32_16x16x32_bf16(a2, bf2[(kk & 1) * 2 + nt], acc2[nt], 0, 0, 0);
        }
        if (STAGE == 2) {
            #pragma unroll
            for (int nt = 0; nt < 2; nt++)
                #pragma unroll
                for (int r = 0; r < 4; r++)
                    vmax = fmaxf(vmax, acc2[nt][r] * bb2[nt].y);
            continue;
        }

        #pragma unroll
        for (int nt = 0; nt < 2; nt++)
            #pragma unroll
            for (int r = 0; r < 4; r++) {
                float h = fmaxf(acc2[nt][r] * bb2[nt].y, 0.f);
                int q = (int)fminf(rintf(h * inv2), 32767.f);
                int al = (q << 24) >> 24;
                int idx = (grp * 4 + r) * 40 + li + nt * 16;
                ah2[idx] = bf16b((float)(q - al));
                al2[idx] = bf16b((float)al);
            }
        asm volatile("" ::: "memory");

        // ---- L3: K=64 stacked (2 chunks, shared B frag) ----
        f32x4 acc3[2];
        #pragma unroll
        for (int nt = 0; nt < 2; nt++)
            acc3[nt] = f32x4{bb3[nt].x, bb3[nt].x, bb3[nt].x, bb3[nt].x};
        #pragma unroll
        for (int kk = 0; kk < 2; kk++) {
            const unsigned short* src = kk ? al2 : ah2;
            s16x8 a3 = *(const s16x8*)(src + li * 40 + grp * 8);
            #pragma unroll
            for (int nt = 0; nt < 2; nt++)
                acc3[nt] = __builtin_amdgcn_mfma_f32_16x16x32_bf16(a3, bf3[nt], acc3[nt], 0, 0, 0);
        }
        if (STAGE == 3) {
            #pragma unroll
            for (int nt = 0; nt < 2; nt++)
                #pragma unroll
                for (int r = 0; r < 4; r++)
                    vmax = fmaxf(vmax, acc3[nt][r] * bb3[nt].y);
            continue;
        }

        #pragma unroll
        for (int nt = 0; nt < 2; nt++)
            #pragma unroll
            for (int r = 0; r < 4; r++) {
                float h = fmaxf(acc3[nt][r] * bb3[nt].y, 0.f);
                int q = (int)fminf(rintf(h * inv3), 32767.f);
                int al = (q << 24) >> 24;
                int idx = (grp * 4 + r) * 40 + li + nt * 16;
                ah3[idx] = bf16b((float)(q - al));
                al3[idx] = bf16b((float)al);
            }
        asm volatile("" ::: "memory");

        // ---- L4: K=64 stacked, one 16-col tile (cols 5..15 zero-weight) ----
        f32x4 acc4 = f32x4{bb4.x, bb4.x, bb4.x, bb4.x};
        #pragma unroll
        for (int kk = 0; kk < 2; kk++) {
            const unsigned short* src = kk ? al3 : ah3;
            s16x8 a4 = *(const s16x8*)(src + li * 40 + grp * 8);
            acc4 = __builtin_amdgcn_mfma_f32_16x16x32_bf16(a4, bf4, acc4, 0, 0, 0);
        }
        if (li < 5) {
            #pragma unroll
            for (int r = 0; r < 4; r++) smx[(grp * 4 + r) * 20 + li] = acc4[r] * bb4.y;
        }
        asm volatile("" ::: "memory");
        if (l < 16) {
            float lg[5];
            #pragma unroll
            for (int c = 0; c < 5; c++) lg[c] = smx[l * 20 + c];
            float m = lg[0];
            #pragma unroll
            for (int c = 1; c < 5; c++) m = fmaxf(m, lg[c]);
            float e[5], ssum = 0.f;
            #pragma unroll
            for (int c = 0; c < 5; c++) { e[c] = expf(lg[c] - m); ssum += e[c]; }
            const float rcp = 1.f / ssum;
            float* dst = out + (row0 + l) * 5;
            #pragma unroll
            for (int c = 0; c < 5; c++) dst[c] = e[c] * rcp;
        }
        asm volatile("" ::: "memory");
    }

    if (STAGE < 4) reduceAndAtomicMax(vmax, slots + STAGE);
}

__global__ __launch_bounds__(256) void k_s1(const float* x, const float* b1, const float* b2,
                                            const float* b3, const float* b4, const float* ws,
                                            unsigned int* slots, float* out) {
    stage_body<1>(x, b1, b2, b3, b4, ws, slots, out);
}
__global__ __launch_bounds__(256) void k_s2(const float* x, const float* b1, const float* b2,
                                            const float* b3, const float* b4, const float* ws,
                                            unsigned int* slots, float* out) {
    stage_body<2>(x, b1, b2, b3, b4, ws, slots, out);
}
__global__ __launch_bounds__(256) void k_s3(const float* x, const float* b1, const float* b2,
                                            const float* b3, const float* b4, const float* ws,
                                            unsigned int* slots, float* out) {
    stage_body<3>(x, b1, b2, b3, b4, ws, slots, out);
}
__global__ __launch_bounds__(256) void k_s4(const float* x, const float* b1, const float* b2,
                                            const float* b3, const float* b4, const float* ws,
                                            unsigned int* slots, float* out) {
    stage_body<4>(x, b1, b2, b3, b4, ws, slots, out);
}

extern "C" void kernel_launch(void* const* d_in, const int* in_sizes, int n_in,
                              void* d_out, int out_size, void* d_ws, size_t ws_size,
                              hipStream_t stream) {
    const float* x  = (const float*)d_in[0];
    const float* W1 = (const float*)d_in[1];
    const float* b1 = (const float*)d_in[2];
    const float* W2 = (const float*)d_in[3];
    const float* b2 = (const float*)d_in[4];
    const float* W3 = (const float*)d_in[5];
    const float* b3 = (const float*)d_in[6];
    const float* W4 = (const float*)d_in[7];
    const float* b4 = (const float*)d_in[8];
    float* out = (float*)d_out;
    float* ws = (float*)d_ws;
    unsigned int* slots = (unsigned int*)d_ws;

    const int B = in_sizes[0] / 16;              // 1 << 20 rows
    const int rowsPerBlock = 4 * TPW * 16;       // 4 waves x 8 tiles x 16 rows = 512
    const int blocks = (B + rowsPerBlock - 1) / rowsPerBlock;  // 2048

    k_quantw<<<1, 256, 0, stream>>>(W1, W2, W3, W4, ws);
    k_absmax<<<2048, 256, 0, stream>>>((const float4*)x, slots, in_sizes[0] / 4);
    k_s1<<<blocks, 256, 0, stream>>>(x, b1, b2, b3, b4, ws, slots, out);
    k_s2<<<blocks, 256, 0, stream>>>(x, b1, b2, b3, b4, ws, slots, out);
    k_s3<<<blocks, 256, 0, stream>>>(x, b1, b2, b3, b4, ws, slots, out);
    k_s4<<<blocks, 256, 0, stream>>>(x, b1, b2, b3, b4, ws, slots, out);
}

// Round 5
// 284.740 us; speedup vs baseline: 2.4944x; 1.1078x over previous
//
#include <hip/hip_runtime.h>
#include <math.h>

#define DEV __device__ __forceinline__

typedef short s16x8 __attribute__((ext_vector_type(8)));
typedef float f32x4 __attribute__((ext_vector_type(4)));

// ---- ws dword layout ----
// [0..3]: reduction slots (bit patterns of non-negative floats)
static constexpr int W1S = 16;   // 64 per-out-row weight scales
static constexpr int W2S = 80;   // 32
static constexpr int W3S = 112;  // 32
static constexpr int W4S = 144;  // 5
static constexpr int F0  = 256;  // 18 A-fragments (weights), each 64 lanes x int4
// frag ids: 0..3 = A1[nt] | 4..11 = A2[mt*4+c] | 12..15 = A3[mt*2+c] | 16..17 = A4[c]

static constexpr int TPW = 8;    // 16-row tiles per wave

DEV float qbias(float b, float bs) {
    float q = rintf(b / bs);
    return fminf(fmaxf(q, -2.147483648e9f), 2.147483648e9f);
}

DEV unsigned short bf16b(float f) {  // values used are exact in bf16 -> truncate
    return (unsigned short)(__float_as_uint(f) >> 16);
}

DEV void reduceAndAtomicMax(float v, unsigned int* slot) {
    #pragma unroll
    for (int off = 32; off; off >>= 1) v = fmaxf(v, __shfl_xor(v, off));
    __shared__ float sm[4];
    const int wid = threadIdx.x >> 6;
    if ((threadIdx.x & 63) == 0) sm[wid] = v;
    __syncthreads();
    if (threadIdx.x == 0) {
        float m = fmaxf(fmaxf(sm[0], sm[1]), fmaxf(sm[2], sm[3]));
        atomicMax(slot, __float_as_uint(m)); // non-negative: bit order == value order
    }
}

// ---- setup: quantize weights, emit k-permuted A-fragments (weights as MFMA A) ----
__global__ __launch_bounds__(256) void k_quantw(const float* __restrict__ W1,
                                                const float* __restrict__ W2,
                                                const float* __restrict__ W3,
                                                const float* __restrict__ W4,
                                                float* __restrict__ wsf) {
    __shared__ int wq1[64 * 16], wq2[32 * 64], wq3[32 * 32], wq4[5 * 32];
    int* wsi = (int*)wsf;
    const int t = threadIdx.x;
    if (t < 4) ((unsigned int*)wsf)[t] = 0u;

    const float* W = nullptr; int row = -1, cols = 0; int* dq = nullptr; float* dsc = nullptr;
    if (t < 64)       { W = W1; row = t;       cols = 16; dq = wq1 + row * 16; dsc = wsf + W1S + row; }
    else if (t < 96)  { W = W2; row = t - 64;  cols = 64; dq = wq2 + row * 64; dsc = wsf + W2S + row; }
    else if (t < 128) { W = W3; row = t - 96;  cols = 32; dq = wq3 + row * 32; dsc = wsf + W3S + row; }
    else if (t < 133) { W = W4; row = t - 128; cols = 32; dq = wq4 + row * 32; dsc = wsf + W4S + row; }
    if (row >= 0) {
        const float* src = W + row * cols;
        float m = 0.f;
        for (int i = 0; i < cols; i++) m = fmaxf(m, fabsf(src[i]));
        float s = fmaxf(m * (1.0f / 127.0f), 1e-8f);
        *dsc = s;
        for (int i = 0; i < cols; i++) {
            float q = fminf(fmaxf(rintf(src[i] / s), -128.f), 127.f);
            dq[i] = (int)q;
        }
    }
    __syncthreads();

    // A-fragment: lane l holds A[row = l&15][k = (l>>4)*8 + e].
    // k-maps (weight duplicated for hi/lo halves of the split activation):
    //  L1: k=8*grp+e -> feature (grp&1)*8 + e           (grp>>1 = hi/lo)
    //  L2/L3/L4 chunk c: k=8*grp+e -> feature 16c + 4*grp + (e&3)  (e>>2 = hi/lo)
    for (int sIdx = t; sIdx < 18 * 64; sIdx += 256) {
        const int f = sIdx >> 6, l = sIdx & 63;
        const int grp = l >> 4, li = l & 15;
        int dw[4];
        #pragma unroll
        for (int d = 0; d < 4; d++) {
            unsigned int hv[2];
            #pragma unroll
            for (int h = 0; h < 2; h++) {
                const int e = 2 * d + h;
                int wv;
                if (f < 4) {                    // A1[nt], rows = out 16nt+li
                    wv = wq1[(f * 16 + li) * 16 + (grp & 1) * 8 + e];
                } else if (f < 12) {            // A2[mt][c]
                    int mt = (f - 4) >> 2, c = (f - 4) & 3;
                    wv = wq2[(mt * 16 + li) * 64 + 16 * c + 4 * grp + (e & 3)];
                } else if (f < 16) {            // A3[mt][c]
                    int mt = (f - 12) >> 1, c = (f - 12) & 1;
                    wv = wq3[(mt * 16 + li) * 32 + 16 * c + 4 * grp + (e & 3)];
                } else {                        // A4[c], rows 5..15 zero
                    int c = f - 16;
                    wv = (li < 5) ? wq4[li * 32 + 16 * c + 4 * grp + (e & 3)] : 0;
                }
                hv[h] = bf16b((float)wv);
            }
            dw[d] = (int)(hv[0] | (hv[1] << 16));
        }
        ((int4*)(wsi + F0))[f * 64 + l] = make_int4(dw[0], dw[1], dw[2], dw[3]);
    }
}

// ---- K0: max|x| ----
__global__ __launch_bounds__(256) void k_absmax(const float4* __restrict__ x,
                                                unsigned int* __restrict__ slots, int n4) {
    float m = 0.f;
    for (int i = blockIdx.x * blockDim.x + threadIdx.x; i < n4; i += gridDim.x * blockDim.x) {
        float4 v = x[i];
        m = fmaxf(m, fmaxf(fmaxf(fabsf(v.x), fabsf(v.y)), fmaxf(fabsf(v.z), fabsf(v.w))));
    }
    reduceAndAtomicMax(m, slots + 0);
}

// quant(+relu) an accumulator value and split q = 256*A + B, both exact in bf16
DEV void qsplit(float acc, float2 c, unsigned& hib, unsigned& lob) {
    float t = fmaxf(fmaf(acc, c.x, c.y), 0.f);   // relu(fma) ; rint after relu == relu after rint
    float q = fminf(rintf(t), 32767.f);
    float A = rintf(q * (1.f / 256.f));          // in [-128,128], exact
    float B = fmaf(A, -256.f, q);                // q - 256A in [-128,128], exact
    hib = __float_as_uint(A * 256.f) >> 16;
    lob = __float_as_uint(B) >> 16;
}

// x-path: quantize to int16 range, split, select hi/lo plane
DEV unsigned qx(float v, float inv0, bool hi) {
    float q = fminf(fmaxf(rintf(v * inv0), -32768.f), 32767.f);
    float A = rintf(q * (1.f / 256.f));
    float B = fmaf(A, -256.f, q);
    float sel = hi ? A * 256.f : B;
    return __float_as_uint(sel) >> 16;
}

template <int STAGE>
DEV void stage_body(const float* __restrict__ x,
                    const float* __restrict__ b1, const float* __restrict__ b2,
                    const float* __restrict__ b3, const float* __restrict__ b4,
                    const float* __restrict__ wsf, unsigned int* __restrict__ slots,
                    float* __restrict__ out) {
    __shared__ float2 QA[64], QB[32], QC[32], QD[16];
    const int t = threadIdx.x;
    const int w = t >> 6, l = t & 63;
    const int grp = l >> 4, li = l & 15;

    const float s0 = fmaxf(__uint_as_float(slots[0]) * (1.f / 32767.f), 1e-8f);
    float s1 = 1.f, s2 = 1.f, s3 = 1.f;
    if (STAGE >= 2) s1 = fmaxf(__uint_as_float(slots[1]) * (1.f / 32767.f), 1e-8f);
    if (STAGE >= 3) s2 = fmaxf(__uint_as_float(slots[2]) * (1.f / 32767.f), 1e-8f);
    if (STAGE >= 4) s3 = fmaxf(__uint_as_float(slots[3]) * (1.f / 32767.f), 1e-8f);
    const float inv0 = 1.f / s0;
    const float inv1 = (STAGE >= 2) ? 1.f / s1 : 0.f;
    const float inv2 = (STAGE >= 3) ? 1.f / s2 : 0.f;
    const float inv3 = (STAGE >= 4) ? 1.f / s3 : 0.f;

    // Per-layer consts: Q-form (c1,c2)=(bs,bias_f)*inv_next for quantized layers,
    // E-form (bs, bias_f) for the exit layer.
    if (t < 64) {
        float bs = wsf[W1S + t] * s0; float bi = qbias(b1[t], bs) * bs;
        QA[t] = (STAGE == 1) ? make_float2(bs, bi) : make_float2(bs * inv1, bi * inv1);
    }
    if (STAGE >= 2 && t < 32) {
        float bs = wsf[W2S + t] * s1; float bi = qbias(b2[t], bs) * bs;
        QB[t] = (STAGE == 2) ? make_float2(bs, bi) : make_float2(bs * inv2, bi * inv2);
    }
    if (STAGE >= 3 && t < 32) {
        float bs = wsf[W3S + t] * s2; float bi = qbias(b3[t], bs) * bs;
        QC[t] = (STAGE == 3) ? make_float2(bs, bi) : make_float2(bs * inv3, bi * inv3);
    }
    if (STAGE >= 4 && t < 16) {
        if (t < 5) { float bs = wsf[W4S + t] * s3; QD[t] = make_float2(bs, qbias(b4[t], bs) * bs); }
        else QD[t] = make_float2(0.f, 0.f);
    }
    __syncthreads();

    // weight A-fragments (persist in VGPRs)
    const int4* fr = (const int4*)((const int*)wsf + F0);
    s16x8 A1[4], A2[2][4], A3[2][2], A4[2];
    #pragma unroll
    for (int nt = 0; nt < 4; nt++) A1[nt] = __builtin_bit_cast(s16x8, fr[nt * 64 + l]);
    if (STAGE >= 2)
        #pragma unroll
        for (int mt = 0; mt < 2; mt++)
            #pragma unroll
            for (int c = 0; c < 4; c++) A2[mt][c] = __builtin_bit_cast(s16x8, fr[(4 + mt * 4 + c) * 64 + l]);
    if (STAGE >= 3)
        #pragma unroll
        for (int mt = 0; mt < 2; mt++)
            #pragma unroll
            for (int c = 0; c < 2; c++) A3[mt][c] = __builtin_bit_cast(s16x8, fr[(12 + mt * 2 + c) * 64 + l]);
    if (STAGE >= 4) {
        A4[0] = __builtin_bit_cast(s16x8, fr[16 * 64 + l]);
        A4[1] = __builtin_bit_cast(s16x8, fr[17 * 64 + l]);
    }

    // per-lane quant consts: feature(nt/mt, grp, r) = 16*nt + 4*grp + r
    float2 cq1[4][4], cq2[2][4], cq3[2][4], e4[4];
    if (STAGE >= 2)
        #pragma unroll
        for (int nt = 0; nt < 4; nt++)
            #pragma unroll
            for (int r = 0; r < 4; r++) cq1[nt][r] = QA[16 * nt + 4 * grp + r];
    if (STAGE >= 3)
        #pragma unroll
        for (int mt = 0; mt < 2; mt++)
            #pragma unroll
            for (int r = 0; r < 4; r++) cq2[mt][r] = QB[16 * mt + 4 * grp + r];
    if (STAGE >= 4) {
        #pragma unroll
        for (int mt = 0; mt < 2; mt++)
            #pragma unroll
            for (int r = 0; r < 4; r++) cq3[mt][r] = QC[16 * mt + 4 * grp + r];
        #pragma unroll
        for (int r = 0; r < 4; r++) e4[r] = QD[4 * grp + r];
    }

    float ma1[4][4], ma2[2][4], ma3[2][4];
    if (STAGE == 1)
        #pragma unroll
        for (int nt = 0; nt < 4; nt++)
            #pragma unroll
            for (int r = 0; r < 4; r++) ma1[nt][r] = -3.402823466e38f;
    if (STAGE == 2)
        #pragma unroll
        for (int mt = 0; mt < 2; mt++)
            #pragma unroll
            for (int r = 0; r < 4; r++) ma2[mt][r] = -3.402823466e38f;
    if (STAGE == 3)
        #pragma unroll
        for (int mt = 0; mt < 2; mt++)
            #pragma unroll
            for (int r = 0; r < 4; r++) ma3[mt][r] = -3.402823466e38f;

    const bool hiLane = (grp < 2);
    const size_t tile0 = ((size_t)blockIdx.x * 4 + w) * (size_t)TPW;

    for (int it = 0; it < TPW; ++it) {
        const size_t row0 = (tile0 + it) * 16;

        // ---- B1 from x: col=li (batch), k=8*grp+e -> feature 8*(grp&1)+e, hi/lo=grp>>1
        s16x8 b1v;
        {
            const float4* xr = (const float4*)(x + (row0 + li) * 16 + (grp & 1) * 8);
            float4 v0 = xr[0], v1 = xr[1];
            float xv[8] = {v0.x, v0.y, v0.z, v0.w, v1.x, v1.y, v1.z, v1.w};
            int dw[4];
            #pragma unroll
            for (int d = 0; d < 4; d++) {
                unsigned p0 = qx(xv[2 * d + 0], inv0, hiLane);
                unsigned p1 = qx(xv[2 * d + 1], inv0, hiLane);
                dw[d] = (int)(p0 | (p1 << 16));
            }
            b1v = __builtin_bit_cast(s16x8, make_int4(dw[0], dw[1], dw[2], dw[3]));
        }

        // ---- L1: D1[nt] lane holds (batch li, feature 16nt+4grp+r) ----
        s16x8 B2f[4];
        #pragma unroll
        for (int nt = 0; nt < 4; nt++) {
            f32x4 acc = {0.f, 0.f, 0.f, 0.f};
            acc = __builtin_amdgcn_mfma_f32_16x16x32_bf16(A1[nt], b1v, acc, 0, 0, 0);
            if (STAGE == 1) {
                #pragma unroll
                for (int r = 0; r < 4; r++) ma1[nt][r] = fmaxf(ma1[nt][r], acc[r]);
            } else {
                unsigned h0, l0, h1, l1, h2, l2, h3, l3;
                qsplit(acc[0], cq1[nt][0], h0, l0);
                qsplit(acc[1], cq1[nt][1], h1, l1);
                qsplit(acc[2], cq1[nt][2], h2, l2);
                qsplit(acc[3], cq1[nt][3], h3, l3);
                B2f[nt] = __builtin_bit_cast(s16x8,
                    make_int4((int)(h0 | (h1 << 16)), (int)(h2 | (h3 << 16)),
                              (int)(l0 | (l1 << 16)), (int)(l2 | (l3 << 16))));
            }
        }
        if (STAGE == 1) continue;

        // ---- L2: chunk c consumes D1-tile nt=c ----
        f32x4 acc2[2] = {{0.f, 0.f, 0.f, 0.f}, {0.f, 0.f, 0.f, 0.f}};
        #pragma unroll
        for (int c = 0; c < 4; c++) {
            acc2[0] = __builtin_amdgcn_mfma_f32_16x16x32_bf16(A2[0][c], B2f[c], acc2[0], 0, 0, 0);
            acc2[1] = __builtin_amdgcn_mfma_f32_16x16x32_bf16(A2[1][c], B2f[c], acc2[1], 0, 0, 0);
        }
        if (STAGE == 2) {
            #pragma unroll
            for (int mt = 0; mt < 2; mt++)
                #pragma unroll
                for (int r = 0; r < 4; r++) ma2[mt][r] = fmaxf(ma2[mt][r], acc2[mt][r]);
            continue;
        }

        s16x8 B3f[2];
        #pragma unroll
        for (int c = 0; c < 2; c++) {
            unsigned h0, l0, h1, l1, h2, l2, h3, l3;
            qsplit(acc2[c][0], cq2[c][0], h0, l0);
            qsplit(acc2[c][1], cq2[c][1], h1, l1);
            qsplit(acc2[c][2], cq2[c][2], h2, l2);
            qsplit(acc2[c][3], cq2[c][3], h3, l3);
            B3f[c] = __builtin_bit_cast(s16x8,
                make_int4((int)(h0 | (h1 << 16)), (int)(h2 | (h3 << 16)),
                          (int)(l0 | (l1 << 16)), (int)(l2 | (l3 << 16))));
        }

        // ---- L3 ----
        f32x4 acc3[2] = {{0.f, 0.f, 0.f, 0.f}, {0.f, 0.f, 0.f, 0.f}};
        #pragma unroll
        for (int c = 0; c < 2; c++) {
            acc3[0] = __builtin_amdgcn_mfma_f32_16x16x32_bf16(A3[0][c], B3f[c], acc3[0], 0, 0, 0);
            acc3[1] = __builtin_amdgcn_mfma_f32_16x16x32_bf16(A3[1][c], B3f[c], acc3[1], 0, 0, 0);
        }
        if (STAGE == 3) {
            #pragma unroll
            for (int mt = 0; mt < 2; mt++)
                #pragma unroll
                for (int r = 0; r < 4; r++) ma3[mt][r] = fmaxf(ma3[mt][r], acc3[mt][r]);
            continue;
        }

        s16x8 B4f[2];
        #pragma unroll
        for (int c = 0; c < 2; c++) {
            unsigned h0, l0, h1, l1, h2, l2, h3, l3;
            qsplit(acc3[c][0], cq3[c][0], h0, l0);
            qsplit(acc3[c][1], cq3[c][1], h1, l1);
            qsplit(acc3[c][2], cq3[c][2], h2, l2);
            qsplit(acc3[c][3], cq3[c][3], h3, l3);
            B4f[c] = __builtin_bit_cast(s16x8,
                make_int4((int)(h0 | (h1 << 16)), (int)(h2 | (h3 << 16)),
                          (int)(l0 | (l1 << 16)), (int)(l2 | (l3 << 16))));
        }

        // ---- L4: logits feature 4grp+r (valid < 5) ----
        f32x4 acc4 = {0.f, 0.f, 0.f, 0.f};
        acc4 = __builtin_amdgcn_mfma_f32_16x16x32_bf16(A4[0], B4f[0], acc4, 0, 0, 0);
        acc4 = __builtin_amdgcn_mfma_f32_16x16x32_bf16(A4[1], B4f[1], acc4, 0, 0, 0);

        float lg0 = fmaf(acc4[0], e4[0].x, e4[0].y);
        float lg1 = fmaf(acc4[1], e4[1].x, e4[1].y);
        float lg2 = fmaf(acc4[2], e4[2].x, e4[2].y);
        float lg3 = fmaf(acc4[3], e4[3].x, e4[3].y);
        float lg4 = __shfl(lg0, li + 16);  // grp1 reg0 = feature 4

        if (l < 16) {
            float m = fmaxf(fmaxf(fmaxf(lg0, lg1), fmaxf(lg2, lg3)), lg4);
            float e0 = __expf(lg0 - m), e1 = __expf(lg1 - m), e2 = __expf(lg2 - m),
                  e3 = __expf(lg3 - m), ee4 = __expf(lg4 - m);
            float r = 1.f / (e0 + e1 + e2 + e3 + ee4);
            float* dst = out + (row0 + l) * 5;
            dst[0] = e0 * r; dst[1] = e1 * r; dst[2] = e2 * r; dst[3] = e3 * r; dst[4] = ee4 * r;
        }
    }

    if (STAGE == 1) {
        float vmax = 0.f;
        #pragma unroll
        for (int nt = 0; nt < 4; nt++)
            #pragma unroll
            for (int r = 0; r < 4; r++) {
                float2 c = QA[16 * nt + 4 * grp + r];
                vmax = fmaxf(vmax, fmaf(ma1[nt][r], c.x, c.y));
            }
        reduceAndAtomicMax(vmax, slots + 1);
    } else if (STAGE == 2) {
        float vmax = 0.f;
        #pragma unroll
        for (int mt = 0; mt < 2; mt++)
            #pragma unroll
            for (int r = 0; r < 4; r++) {
                float2 c = QB[16 * mt + 4 * grp + r];
                vmax = fmaxf(vmax, fmaf(ma2[mt][r], c.x, c.y));
            }
        reduceAndAtomicMax(vmax, slots + 2);
    } else if (STAGE == 3) {
        float vmax = 0.f;
        #pragma unroll
        for (int mt = 0; mt < 2; mt++)
            #pragma unroll
            for (int r = 0; r < 4; r++) {
                float2 c = QC[16 * mt + 4 * grp + r];
                vmax = fmaxf(vmax, fmaf(ma3[mt][r], c.x, c.y));
            }
        reduceAndAtomicMax(vmax, slots + 3);
    }
}

__global__ __launch_bounds__(256, 4) void k_s1(const float* x, const float* b1, const float* b2,
                                               const float* b3, const float* b4, const float* ws,
                                               unsigned int* slots, float* out) {
    stage_body<1>(x, b1, b2, b3, b4, ws, slots, out);
}
__global__ __launch_bounds__(256, 3) void k_s2(const float* x, const float* b1, const float* b2,
                                               const float* b3, const float* b4, const float* ws,
                                               unsigned int* slots, float* out) {
    stage_body<2>(x, b1, b2, b3, b4, ws, slots, out);
}
__global__ __launch_bounds__(256, 2) void k_s3(const float* x, const float* b1, const float* b2,
                                               const float* b3, const float* b4, const float* ws,
                                               unsigned int* slots, float* out) {
    stage_body<3>(x, b1, b2, b3, b4, ws, slots, out);
}
__global__ __launch_bounds__(256, 2) void k_s4(const float* x, const float* b1, const float* b2,
                                               const float* b3, const float* b4, const float* ws,
                                               unsigned int* slots, float* out) {
    stage_body<4>(x, b1, b2, b3, b4, ws, slots, out);
}

extern "C" void kernel_launch(void* const* d_in, const int* in_sizes, int n_in,
                              void* d_out, int out_size, void* d_ws, size_t ws_size,
                              hipStream_t stream) {
    const float* x  = (const float*)d_in[0];
    const float* W1 = (const float*)d_in[1];
    const float* b1 = (const float*)d_in[2];
    const float* W2 = (const float*)d_in[3];
    const float* b2 = (const float*)d_in[4];
    const float* W3 = (const float*)d_in[5];
    const float* b3 = (const float*)d_in[6];
    const float* W4 = (const float*)d_in[7];
    const float* b4 = (const float*)d_in[8];
    float* out = (float*)d_out;
    float* ws = (float*)d_ws;
    unsigned int* slots = (unsigned int*)d_ws;

    const int B = in_sizes[0] / 16;              // 1 << 20 rows
    const int rowsPerBlock = 4 * TPW * 16;       // 512
    const int blocks = (B + rowsPerBlock - 1) / rowsPerBlock;  // 2048

    k_quantw<<<1, 256, 0, stream>>>(W1, W2, W3, W4, ws);
    k_absmax<<<2048, 256, 0, stream>>>((const float4*)x, slots, in_sizes[0] / 4);
    k_s1<<<blocks, 256, 0, stream>>>(x, b1, b2, b3, b4, ws, slots, out);
    k_s2<<<blocks, 256, 0, stream>>>(x, b1, b2, b3, b4, ws, slots, out);
    k_s3<<<blocks, 256, 0, stream>>>(x, b1, b2, b3, b4, ws, slots, out);
    k_s4<<<blocks, 256, 0, stream>>>(x, b1, b2, b3, b4, ws, slots, out);
}

// Round 6
// 275.442 us; speedup vs baseline: 2.5786x; 1.0338x over previous
//
#include <hip/hip_runtime.h>
#include <math.h>

#define DEV __device__ __forceinline__

typedef short s16x8 __attribute__((ext_vector_type(8)));
typedef float f32x4 __attribute__((ext_vector_type(4)));

// ---- ws dword layout ----
// [0..3]: reduction slots (bit patterns of non-negative floats)
static constexpr int W1S = 16;   // 64 per-out-row weight scales
static constexpr int W2S = 80;   // 32
static constexpr int W3S = 112;  // 32
static constexpr int W4S = 144;  // 5
static constexpr int F0  = 256;  // 18 A-fragments (weights), each 64 lanes x int4
// frag ids: 0..3 = A1[nt] | 4..11 = A2[mt*4+c] | 12..15 = A3[mt*2+c] | 16..17 = A4[c]

static constexpr int TPW = 8;    // 16-row tiles per wave

DEV float qbias(float b, float bs) {
    float q = rintf(b / bs);
    return fminf(fmaxf(q, -2.147483648e9f), 2.147483648e9f);
}

DEV unsigned short bf16b(float f) {  // values used are exact in bf16 -> truncate
    return (unsigned short)(__float_as_uint(f) >> 16);
}

DEV void reduceAndAtomicMax(float v, unsigned int* slot) {
    #pragma unroll
    for (int off = 32; off; off >>= 1) v = fmaxf(v, __shfl_xor(v, off));
    __shared__ float sm[4];
    const int wid = threadIdx.x >> 6;
    if ((threadIdx.x & 63) == 0) sm[wid] = v;
    __syncthreads();
    if (threadIdx.x == 0) {
        float m = fmaxf(fmaxf(sm[0], sm[1]), fmaxf(sm[2], sm[3]));
        atomicMax(slot, __float_as_uint(m)); // non-negative: bit order == value order
    }
}

// ---- setup: quantize weights, emit k-permuted A-fragments (weights as MFMA A) ----
__global__ __launch_bounds__(256) void k_quantw(const float* __restrict__ W1,
                                                const float* __restrict__ W2,
                                                const float* __restrict__ W3,
                                                const float* __restrict__ W4,
                                                float* __restrict__ wsf) {
    __shared__ int wq1[64 * 16], wq2[32 * 64], wq3[32 * 32], wq4[5 * 32];
    int* wsi = (int*)wsf;
    const int t = threadIdx.x;
    if (t < 4) ((unsigned int*)wsf)[t] = 0u;

    const float* W = nullptr; int row = -1, cols = 0; int* dq = nullptr; float* dsc = nullptr;
    if (t < 64)       { W = W1; row = t;       cols = 16; dq = wq1 + row * 16; dsc = wsf + W1S + row; }
    else if (t < 96)  { W = W2; row = t - 64;  cols = 64; dq = wq2 + row * 64; dsc = wsf + W2S + row; }
    else if (t < 128) { W = W3; row = t - 96;  cols = 32; dq = wq3 + row * 32; dsc = wsf + W3S + row; }
    else if (t < 133) { W = W4; row = t - 128; cols = 32; dq = wq4 + row * 32; dsc = wsf + W4S + row; }
    if (row >= 0) {
        const float* src = W + row * cols;
        float m = 0.f;
        for (int i = 0; i < cols; i++) m = fmaxf(m, fabsf(src[i]));
        float s = fmaxf(m * (1.0f / 127.0f), 1e-8f);
        *dsc = s;
        for (int i = 0; i < cols; i++) {
            float q = fminf(fmaxf(rintf(src[i] / s), -128.f), 127.f);
            dq[i] = (int)q;
        }
    }
    __syncthreads();

    // A-fragment: lane l holds A[row = l&15][k = (l>>4)*8 + e].
    // k-maps (weight duplicated for hi/lo halves of the split activation):
    //  L1: k=8*grp+e -> feature (grp&1)*8 + e           (grp>>1 = hi/lo)
    //  L2/L3/L4 chunk c: k=8*grp+e -> feature 16c + 4*grp + (e&3)  (e>>2 = hi/lo)
    for (int sIdx = t; sIdx < 18 * 64; sIdx += 256) {
        const int f = sIdx >> 6, l = sIdx & 63;
        const int grp = l >> 4, li = l & 15;
        int dw[4];
        #pragma unroll
        for (int d = 0; d < 4; d++) {
            unsigned int hv[2];
            #pragma unroll
            for (int h = 0; h < 2; h++) {
                const int e = 2 * d + h;
                int wv;
                if (f < 4) {                    // A1[nt], rows = out 16nt+li
                    wv = wq1[(f * 16 + li) * 16 + (grp & 1) * 8 + e];
                } else if (f < 12) {            // A2[mt][c]
                    int mt = (f - 4) >> 2, c = (f - 4) & 3;
                    wv = wq2[(mt * 16 + li) * 64 + 16 * c + 4 * grp + (e & 3)];
                } else if (f < 16) {            // A3[mt][c]
                    int mt = (f - 12) >> 1, c = (f - 12) & 1;
                    wv = wq3[(mt * 16 + li) * 32 + 16 * c + 4 * grp + (e & 3)];
                } else {                        // A4[c], rows 5..15 zero
                    int c = f - 16;
                    wv = (li < 5) ? wq4[li * 32 + 16 * c + 4 * grp + (e & 3)] : 0;
                }
                hv[h] = bf16b((float)wv);
            }
            dw[d] = (int)(hv[0] | (hv[1] << 16));
        }
        ((int4*)(wsi + F0))[f * 64 + l] = make_int4(dw[0], dw[1], dw[2], dw[3]);
    }
}

// ---- K0: max|x| ----
__global__ __launch_bounds__(256) void k_absmax(const float4* __restrict__ x,
                                                unsigned int* __restrict__ slots, int n4) {
    float m = 0.f;
    for (int i = blockIdx.x * blockDim.x + threadIdx.x; i < n4; i += gridDim.x * blockDim.x) {
        float4 v = x[i];
        m = fmaxf(m, fmaxf(fmaxf(fabsf(v.x), fabsf(v.y)), fmaxf(fabsf(v.z), fabsf(v.w))));
    }
    reduceAndAtomicMax(m, slots + 0);
}

// pack bf16 bits of two low16-zero floats into one dword: {b0>>16, b1>>16}
DEV int packhi(float q0, float q1) {
    return (int)__builtin_amdgcn_perm(__float_as_uint(q1), __float_as_uint(q0), 0x07060302u);
}

// quant(+relu+clamp via med3) + truncation split, two values -> hi dword + lo dword
DEV void qsplit2(float a0, float a1, float2 c0, float2 c1, int& hw, int& lw) {
    float t0 = fmaf(a0, c0.x, c0.y);
    float t1 = fmaf(a1, c1.x, c1.y);
    float q0 = fminf(fmaxf(rintf(t0), 0.f), 32767.f);      // -> v_med3_f32
    float q1 = fminf(fmaxf(rintf(t1), 0.f), 32767.f);
    float h0 = __uint_as_float(__float_as_uint(q0) & 0xFFFF0000u); // top 8 sig bits
    float h1 = __uint_as_float(__float_as_uint(q1) & 0xFFFF0000u);
    hw = packhi(h0, h1);
    lw = packhi(q0 - h0, q1 - h1);  // residual <= 7 sig bits, bf16-exact
}

// build next-layer B-fragment from one acc tile (4 values) + per-value consts
DEV s16x8 mkfrag(f32x4 acc, const float2* cq) {
    int h01, h23, l01, l23;
    qsplit2(acc[0], acc[1], cq[0], cq[1], h01, l01);
    qsplit2(acc[2], acc[3], cq[2], cq[3], h23, l23);
    return __builtin_bit_cast(s16x8, make_int4(h01, h23, l01, l23));
}

// x-path: quantize to int16 range, truncation split, select plane
DEV float qxsel(float v, float inv0, bool hi) {
    float q = rintf(v * inv0);
    q = fminf(fmaxf(q, -32768.f), 32767.f);                // -> v_med3_f32
    float h = __uint_as_float(__float_as_uint(q) & 0xFFFF0000u);
    return hi ? h : (q - h);
}

template <int STAGE>
DEV void stage_body(const float* __restrict__ x,
                    const float* __restrict__ b1, const float* __restrict__ b2,
                    const float* __restrict__ b3, const float* __restrict__ b4,
                    const float* __restrict__ wsf, unsigned int* __restrict__ slots,
                    float* __restrict__ out) {
    __shared__ float2 QA[64], QB[32], QC[32], QD[16];
    const int t = threadIdx.x;
    const int w = t >> 6, l = t & 63;
    const int grp = l >> 4, li = l & 15;

    const float s0 = fmaxf(__uint_as_float(slots[0]) * (1.f / 32767.f), 1e-8f);
    float s1 = 1.f, s2 = 1.f, s3 = 1.f;
    if (STAGE >= 2) s1 = fmaxf(__uint_as_float(slots[1]) * (1.f / 32767.f), 1e-8f);
    if (STAGE >= 3) s2 = fmaxf(__uint_as_float(slots[2]) * (1.f / 32767.f), 1e-8f);
    if (STAGE >= 4) s3 = fmaxf(__uint_as_float(slots[3]) * (1.f / 32767.f), 1e-8f);
    const float inv0 = 1.f / s0;
    const float inv1 = (STAGE >= 2) ? 1.f / s1 : 0.f;
    const float inv2 = (STAGE >= 3) ? 1.f / s2 : 0.f;
    const float inv3 = (STAGE >= 4) ? 1.f / s3 : 0.f;

    if (t < 64) {
        float bs = wsf[W1S + t] * s0; float bi = qbias(b1[t], bs) * bs;
        QA[t] = (STAGE == 1) ? make_float2(bs, bi) : make_float2(bs * inv1, bi * inv1);
    }
    if (STAGE >= 2 && t < 32) {
        float bs = wsf[W2S + t] * s1; float bi = qbias(b2[t], bs) * bs;
        QB[t] = (STAGE == 2) ? make_float2(bs, bi) : make_float2(bs * inv2, bi * inv2);
    }
    if (STAGE >= 3 && t < 32) {
        float bs = wsf[W3S + t] * s2; float bi = qbias(b3[t], bs) * bs;
        QC[t] = (STAGE == 3) ? make_float2(bs, bi) : make_float2(bs * inv3, bi * inv3);
    }
    if (STAGE >= 4 && t < 16) {
        if (t < 5) { float bs = wsf[W4S + t] * s3; QD[t] = make_float2(bs, qbias(b4[t], bs) * bs); }
        else QD[t] = make_float2(0.f, 0.f);
    }
    __syncthreads();

    // weight A-fragments (persist in VGPRs)
    const int4* fr = (const int4*)((const int*)wsf + F0);
    s16x8 A1[4], A2[2][4], A3[2][2], A4[2];
    #pragma unroll
    for (int nt = 0; nt < 4; nt++) A1[nt] = __builtin_bit_cast(s16x8, fr[nt * 64 + l]);
    if (STAGE >= 2)
        #pragma unroll
        for (int mt = 0; mt < 2; mt++)
            #pragma unroll
            for (int c = 0; c < 4; c++) A2[mt][c] = __builtin_bit_cast(s16x8, fr[(4 + mt * 4 + c) * 64 + l]);
    if (STAGE >= 3)
        #pragma unroll
        for (int mt = 0; mt < 2; mt++)
            #pragma unroll
            for (int c = 0; c < 2; c++) A3[mt][c] = __builtin_bit_cast(s16x8, fr[(12 + mt * 2 + c) * 64 + l]);
    if (STAGE >= 4) {
        A4[0] = __builtin_bit_cast(s16x8, fr[16 * 64 + l]);
        A4[1] = __builtin_bit_cast(s16x8, fr[17 * 64 + l]);
    }

    // per-lane quant consts: feature(nt/mt, grp, r) = 16*nt + 4*grp + r
    float2 cq1[4][4], cq2[2][4], cq3[2][4], e4[4];
    if (STAGE >= 2)
        #pragma unroll
        for (int nt = 0; nt < 4; nt++)
            #pragma unroll
            for (int r = 0; r < 4; r++) cq1[nt][r] = QA[16 * nt + 4 * grp + r];
    if (STAGE >= 3)
        #pragma unroll
        for (int mt = 0; mt < 2; mt++)
            #pragma unroll
            for (int r = 0; r < 4; r++) cq2[mt][r] = QB[16 * mt + 4 * grp + r];
    if (STAGE >= 4) {
        #pragma unroll
        for (int mt = 0; mt < 2; mt++)
            #pragma unroll
            for (int r = 0; r < 4; r++) cq3[mt][r] = QC[16 * mt + 4 * grp + r];
        #pragma unroll
        for (int r = 0; r < 4; r++) e4[r] = QD[4 * grp + r];
    }

    float ma1[4][4], ma2[2][4], ma3[2][4];
    if (STAGE == 1)
        #pragma unroll
        for (int nt = 0; nt < 4; nt++)
            #pragma unroll
            for (int r = 0; r < 4; r++) ma1[nt][r] = -3.402823466e38f;
    if (STAGE == 2)
        #pragma unroll
        for (int mt = 0; mt < 2; mt++)
            #pragma unroll
            for (int r = 0; r < 4; r++) ma2[mt][r] = -3.402823466e38f;
    if (STAGE == 3)
        #pragma unroll
        for (int mt = 0; mt < 2; mt++)
            #pragma unroll
            for (int r = 0; r < 4; r++) ma3[mt][r] = -3.402823466e38f;

    const bool hiLane = (grp < 2);
    const size_t tile0 = ((size_t)blockIdx.x * 4 + w) * (size_t)TPW;

    // software prefetch of tile 0's x
    float4 px0, px1;
    {
        const float4* xr = (const float4*)(x + (tile0 * 16 + li) * 16 + (grp & 1) * 8);
        px0 = xr[0]; px1 = xr[1];
    }

    for (int it = 0; it < TPW; ++it) {
        const size_t row0 = (tile0 + it) * 16;
        float4 v0 = px0, v1 = px1;
        if (it + 1 < TPW) {  // issue next tile's loads early; compute below hides latency
            const float4* xr = (const float4*)(x + ((tile0 + it + 1) * 16 + li) * 16 + (grp & 1) * 8);
            px0 = xr[0]; px1 = xr[1];
        }

        // ---- B1 from x: col=li (batch), k=8*grp+e -> feature 8*(grp&1)+e, hi/lo=grp>>1
        s16x8 b1v;
        {
            float p0 = qxsel(v0.x, inv0, hiLane), p1 = qxsel(v0.y, inv0, hiLane);
            float p2 = qxsel(v0.z, inv0, hiLane), p3 = qxsel(v0.w, inv0, hiLane);
            float p4 = qxsel(v1.x, inv0, hiLane), p5 = qxsel(v1.y, inv0, hiLane);
            float p6 = qxsel(v1.z, inv0, hiLane), p7 = qxsel(v1.w, inv0, hiLane);
            b1v = __builtin_bit_cast(s16x8,
                make_int4(packhi(p0, p1), packhi(p2, p3), packhi(p4, p5), packhi(p6, p7)));
        }

        // ---- L1: D1[nt] lane holds (batch li, feature 16nt+4grp+r) ----
        s16x8 B2f[4];
        #pragma unroll
        for (int nt = 0; nt < 4; nt++) {
            f32x4 acc = {0.f, 0.f, 0.f, 0.f};
            acc = __builtin_amdgcn_mfma_f32_16x16x32_bf16(A1[nt], b1v, acc, 0, 0, 0);
            if (STAGE == 1) {
                #pragma unroll
                for (int r = 0; r < 4; r++) ma1[nt][r] = fmaxf(ma1[nt][r], acc[r]);
            } else {
                B2f[nt] = mkfrag(acc, cq1[nt]);
            }
        }
        if (STAGE == 1) continue;

        // ---- L2: chunk c consumes D1-tile nt=c ----
        f32x4 acc2[2] = {{0.f, 0.f, 0.f, 0.f}, {0.f, 0.f, 0.f, 0.f}};
        #pragma unroll
        for (int c = 0; c < 4; c++) {
            acc2[0] = __builtin_amdgcn_mfma_f32_16x16x32_bf16(A2[0][c], B2f[c], acc2[0], 0, 0, 0);
            acc2[1] = __builtin_amdgcn_mfma_f32_16x16x32_bf16(A2[1][c], B2f[c], acc2[1], 0, 0, 0);
        }
        if (STAGE == 2) {
            #pragma unroll
            for (int mt = 0; mt < 2; mt++)
                #pragma unroll
                for (int r = 0; r < 4; r++) ma2[mt][r] = fmaxf(ma2[mt][r], acc2[mt][r]);
            continue;
        }

        s16x8 B3f[2];
        #pragma unroll
        for (int c = 0; c < 2; c++) B3f[c] = mkfrag(acc2[c], cq2[c]);

        // ---- L3 ----
        f32x4 acc3[2] = {{0.f, 0.f, 0.f, 0.f}, {0.f, 0.f, 0.f, 0.f}};
        #pragma unroll
        for (int c = 0; c < 2; c++) {
            acc3[0] = __builtin_amdgcn_mfma_f32_16x16x32_bf16(A3[0][c], B3f[c], acc3[0], 0, 0, 0);
            acc3[1] = __builtin_amdgcn_mfma_f32_16x16x32_bf16(A3[1][c], B3f[c], acc3[1], 0, 0, 0);
        }
        if (STAGE == 3) {
            #pragma unroll
            for (int mt = 0; mt < 2; mt++)
                #pragma unroll
                for (int r = 0; r < 4; r++) ma3[mt][r] = fmaxf(ma3[mt][r], acc3[mt][r]);
            continue;
        }

        s16x8 B4f[2];
        #pragma unroll
        for (int c = 0; c < 2; c++) B4f[c] = mkfrag(acc3[c], cq3[c]);

        // ---- L4: logits feature 4grp+r (valid < 5) ----
        f32x4 acc4 = {0.f, 0.f, 0.f, 0.f};
        acc4 = __builtin_amdgcn_mfma_f32_16x16x32_bf16(A4[0], B4f[0], acc4, 0, 0, 0);
        acc4 = __builtin_amdgcn_mfma_f32_16x16x32_bf16(A4[1], B4f[1], acc4, 0, 0, 0);

        float lg0 = fmaf(acc4[0], e4[0].x, e4[0].y);
        float lg1 = fmaf(acc4[1], e4[1].x, e4[1].y);
        float lg2 = fmaf(acc4[2], e4[2].x, e4[2].y);
        float lg3 = fmaf(acc4[3], e4[3].x, e4[3].y);
        float lg4 = __shfl(lg0, li + 16);  // grp1 reg0 = feature 4

        if (l < 16) {
            float m = fmaxf(fmaxf(fmaxf(lg0, lg1), fmaxf(lg2, lg3)), lg4);
            float e0 = __expf(lg0 - m), e1 = __expf(lg1 - m), e2 = __expf(lg2 - m),
                  e3 = __expf(lg3 - m), ee4 = __expf(lg4 - m);
            float r = 1.f / (e0 + e1 + e2 + e3 + ee4);
            float* dst = out + (row0 + l) * 5;
            dst[0] = e0 * r; dst[1] = e1 * r; dst[2] = e2 * r; dst[3] = e3 * r; dst[4] = ee4 * r;
        }
    }

    if (STAGE == 1) {
        float vmax = 0.f;
        #pragma unroll
        for (int nt = 0; nt < 4; nt++)
            #pragma unroll
            for (int r = 0; r < 4; r++) {
                float2 c = QA[16 * nt + 4 * grp + r];
                vmax = fmaxf(vmax, fmaf(ma1[nt][r], c.x, c.y));
            }
        reduceAndAtomicMax(vmax, slots + 1);
    } else if (STAGE == 2) {
        float vmax = 0.f;
        #pragma unroll
        for (int mt = 0; mt < 2; mt++)
            #pragma unroll
            for (int r = 0; r < 4; r++) {
                float2 c = QB[16 * mt + 4 * grp + r];
                vmax = fmaxf(vmax, fmaf(ma2[mt][r], c.x, c.y));
            }
        reduceAndAtomicMax(vmax, slots + 2);
    } else if (STAGE == 3) {
        float vmax = 0.f;
        #pragma unroll
        for (int mt = 0; mt < 2; mt++)
            #pragma unroll
            for (int r = 0; r < 4; r++) {
                float2 c = QC[16 * mt + 4 * grp + r];
                vmax = fmaxf(vmax, fmaf(ma3[mt][r], c.x, c.y));
            }
        reduceAndAtomicMax(vmax, slots + 3);
    }
}

__global__ __launch_bounds__(256, 4) void k_s1(const float* x, const float* b1, const float* b2,
                                               const float* b3, const float* b4, const float* ws,
                                               unsigned int* slots, float* out) {
    stage_body<1>(x, b1, b2, b3, b4, ws, slots, out);
}
__global__ __launch_bounds__(256, 3) void k_s2(const float* x, const float* b1, const float* b2,
                                               const float* b3, const float* b4, const float* ws,
                                               unsigned int* slots, float* out) {
    stage_body<2>(x, b1, b2, b3, b4, ws, slots, out);
}
__global__ __launch_bounds__(256, 2) void k_s3(const float* x, const float* b1, const float* b2,
                                               const float* b3, const float* b4, const float* ws,
                                               unsigned int* slots, float* out) {
    stage_body<3>(x, b1, b2, b3, b4, ws, slots, out);
}
__global__ __launch_bounds__(256, 2) void k_s4(const float* x, const float* b1, const float* b2,
                                               const float* b3, const float* b4, const float* ws,
                                               unsigned int* slots, float* out) {
    stage_body<4>(x, b1, b2, b3, b4, ws, slots, out);
}

extern "C" void kernel_launch(void* const* d_in, const int* in_sizes, int n_in,
                              void* d_out, int out_size, void* d_ws, size_t ws_size,
                              hipStream_t stream) {
    const float* x  = (const float*)d_in[0];
    const float* W1 = (const float*)d_in[1];
    const float* b1 = (const float*)d_in[2];
    const float* W2 = (const float*)d_in[3];
    const float* b2 = (const float*)d_in[4];
    const float* W3 = (const float*)d_in[5];
    const float* b3 = (const float*)d_in[6];
    const float* W4 = (const float*)d_in[7];
    const float* b4 = (const float*)d_in[8];
    float* out = (float*)d_out;
    float* ws = (float*)d_ws;
    unsigned int* slots = (unsigned int*)d_ws;

    const int B = in_sizes[0] / 16;              // 1 << 20 rows
    const int rowsPerBlock = 4 * TPW * 16;       // 512
    const int blocks = (B + rowsPerBlock - 1) / rowsPerBlock;  // 2048

    k_quantw<<<1, 256, 0, stream>>>(W1, W2, W3, W4, ws);
    k_absmax<<<2048, 256, 0, stream>>>((const float4*)x, slots, in_sizes[0] / 4);
    k_s1<<<blocks, 256, 0, stream>>>(x, b1, b2, b3, b4, ws, slots, out);
    k_s2<<<blocks, 256, 0, stream>>>(x, b1, b2, b3, b4, ws, slots, out);
    k_s3<<<blocks, 256, 0, stream>>>(x, b1, b2, b3, b4, ws, slots, out);
    k_s4<<<blocks, 256, 0, stream>>>(x, b1, b2, b3, b4, ws, slots, out);
}